// Round 1
// baseline (1849.338 us; speedup 1.0000x reference)
//
#include <hip/hip_runtime.h>
#include <stdint.h>

#define S_LEN 2048
#define DMODEL 1024
#define NH 16
#define DKH 64

typedef unsigned short u16;
using short8 = __attribute__((ext_vector_type(8))) short;
using f32x4  = __attribute__((ext_vector_type(4))) float;

// fold 1/sqrt(DK) * log2(e) into Wq so softmax runs in exp2 domain
#define QSCALE 0.18033688011112042f

__device__ __forceinline__ u16 f2bf(float f) {
  union { float f; uint32_t u; } x{f};
  uint32_t r = x.u + 0x7fffu + ((x.u >> 16) & 1u);
  return (u16)(r >> 16);
}

// ---------------- f32 -> bf16 convert (vectorized x4) ----------------
__global__ __launch_bounds__(256) void cvt_bf16_kernel(const float* __restrict__ src,
                                                       u16* __restrict__ dst, int n4) {
  int i = blockIdx.x * 256 + threadIdx.x;
  if (i >= n4) return;
  float4 v = ((const float4*)src)[i];
  uint32_t p0 = (uint32_t)f2bf(v.x) | ((uint32_t)f2bf(v.y) << 16);
  uint32_t p1 = (uint32_t)f2bf(v.z) | ((uint32_t)f2bf(v.w) << 16);
  ((uint2*)dst)[i] = make_uint2(p0, p1);
}

// ---------------- W[k][n] f32 -> WT[n][k] bf16 (scaled) ----------------
__global__ __launch_bounds__(256) void transpose_cvt_kernel(const float* __restrict__ src,
                                                            u16* __restrict__ dst, float scale) {
  __shared__ float tile[32][33];
  int tx = threadIdx.x, ty = threadIdx.y;
  int n0 = blockIdx.x * 32;   // src col block (n)
  int k0 = blockIdx.y * 32;   // src row block (k)
  for (int j = ty; j < 32; j += 8)
    tile[j][tx] = src[(size_t)(k0 + j) * DMODEL + n0 + tx];
  __syncthreads();
  for (int j = ty; j < 32; j += 8)
    dst[(size_t)(n0 + j) * DMODEL + k0 + tx] = f2bf(tile[tx][j] * scale);
}

// ---------------- 128x128-tile bf16 MFMA GEMM ----------------
// C[M=4096,N=1024] = A[M,K=1024] * WT[N,K]^T, epilogue per mode:
//  mode 0: bf16 out at [B,H,S,DK]   (Q / K heads)
//  mode 1: bf16 out at [B,H,DK,S]   (V transposed)
//  mode 2: f32 out row-major [M,N]  (final projection)
struct GemmArg {
  const u16* A; const u16* W; const float* bias; void* out;
  float biasScale; int mode;
};
struct GemmArgs3 { GemmArg g[3]; };

__global__ __launch_bounds__(256, 3) void gemm128_kernel(GemmArgs3 args) {
  const GemmArg ga = args.g[blockIdx.z];
  __shared__ __align__(16) u16 As[128 * 32];
  __shared__ __align__(16) u16 Bs[128 * 32];
  const int tid = threadIdx.x;
  const int lane = tid & 63, w = tid >> 6;
  const int quad = lane >> 4, l15 = lane & 15;
  const int wm = (w & 1) * 64, wn = (w >> 1) * 64;
  const int m0 = blockIdx.y * 128, n0 = blockIdx.x * 128;

  f32x4 acc[4][4] = {};

  for (int kb = 0; kb < DMODEL; kb += 32) {
    short8 ta[2], tb[2];
#pragma unroll
    for (int i = 0; i < 2; ++i) {
      int u = i * 256 + tid;
      int row = u >> 2, cc = u & 3;
      int cs = cc ^ ((row >> 2) & 3);          // 16B-chunk xor swizzle
      ta[i] = *(const short8*)(ga.A + (size_t)(m0 + row) * DMODEL + kb + cs * 8);
      tb[i] = *(const short8*)(ga.W + (size_t)(n0 + row) * DMODEL + kb + cs * 8);
    }
    __syncthreads();
#pragma unroll
    for (int i = 0; i < 2; ++i) {
      int u = i * 256 + tid;
      *(short8*)((char*)As + u * 16) = ta[i];
      *(short8*)((char*)Bs + u * 16) = tb[i];
    }
    __syncthreads();
    short8 af[4], bf[4];
#pragma unroll
    for (int t = 0; t < 4; ++t) {
      int ra = wm + t * 16 + l15;
      int ca = quad ^ ((ra >> 2) & 3);
      af[t] = *(const short8*)((const char*)As + ra * 64 + ca * 16);
      int rb = wn + t * 16 + l15;
      int cb = quad ^ ((rb >> 2) & 3);
      bf[t] = *(const short8*)((const char*)Bs + rb * 64 + cb * 16);
    }
#pragma unroll
    for (int mt = 0; mt < 4; ++mt)
#pragma unroll
      for (int nt = 0; nt < 4; ++nt)
        acc[mt][nt] = __builtin_amdgcn_mfma_f32_16x16x32_bf16(af[mt], bf[nt], acc[mt][nt], 0, 0, 0);
  }

  float bsv[4];
#pragma unroll
  for (int nt = 0; nt < 4; ++nt)
    bsv[nt] = ga.bias[n0 + wn + nt * 16 + l15] * ga.biasScale;

#pragma unroll
  for (int mt = 0; mt < 4; ++mt) {
#pragma unroll
    for (int nt = 0; nt < 4; ++nt) {
      int gcol = n0 + wn + nt * 16 + l15;
#pragma unroll
      for (int r = 0; r < 4; ++r) {
        int grow = m0 + wm + mt * 16 + quad * 4 + r;   // C/D: row = quad*4+reg, col = lane&15
        float v = acc[mt][nt][r] + bsv[nt];
        if (ga.mode == 2) {
          ((float*)ga.out)[(size_t)grow * DMODEL + gcol] = v;
        } else {
          int bb = grow >> 11, ss = grow & 2047;
          int hh = gcol >> 6, dd = gcol & 63;
          u16* ob = (u16*)ga.out;
          if (ga.mode == 0)
            ob[((size_t)((bb * NH + hh) * S_LEN + ss) << 6) + dd] = f2bf(v);
          else
            ob[((size_t)((bb * NH + hh) * DKH + dd)) * S_LEN + ss] = f2bf(v);
        }
      }
    }
  }
}

// ---------------- fused attention ----------------
// grid.x = b*H+h (32)  [keeps one head-group per XCD for K/V L2 residency]
// grid.y = q-tile of 64 rows (32); 4 waves, 16 q-rows each; two-pass softmax.
__global__ __launch_bounds__(256, 3) void attn_kernel(
    const u16* __restrict__ Qh, const u16* __restrict__ Kh,
    const u16* __restrict__ VT, const int* __restrict__ mask,
    const float* __restrict__ bias, float* __restrict__ pout,
    u16* __restrict__ Oout) {
  __shared__ __align__(16) u16 Ks[128 * 64];      // [key][dk], xor-swizzled 16B chunks
  __shared__ __align__(16) u16 Vs[64 * 128];      // [dk][key], xor-swizzled
  __shared__ __align__(16) u16 Ps[4][16 * 136];   // per-wave P tile, padded stride

  const int tid = threadIdx.x;
  const int lane = tid & 63, w = tid >> 6;
  const int quad = lane >> 4, l15 = lane & 15;
  const int bh = blockIdx.x;
  const int b = bh >> 4, h = bh & 15;
  const int qt = blockIdx.y;
  const int qw = qt * 64 + w * 16;                 // wave's first q row

  const u16* Qb = Qh + (size_t)bh * S_LEN * DKH;
  const u16* Kb = Kh + (size_t)bh * S_LEN * DKH;
  const u16* Vb = VT + (size_t)bh * DKH * S_LEN;
  const int* mb = mask + b * S_LEN;

  short8 qf0, qf1;                                 // A-frag: row=lane&15, k=quad*8+j (+32)
  {
    const u16* qp = Qb + (size_t)(qw + l15) * DKH + quad * 8;
    qf0 = *(const short8*)qp;
    qf1 = *(const short8*)(qp + 32);
  }

  float m[4], l[4];
#pragma unroll
  for (int r = 0; r < 4; ++r) { m[r] = -1e30f; l[r] = 0.f; }

  // ---- pass A: per-lane online (m,l) over all keys ----
  for (int c = 0; c < 16; ++c) {
    const int kb = c * 128;
    short8 st[4];
#pragma unroll
    for (int i = 0; i < 4; ++i) {
      int u = i * 256 + tid;
      int row = u >> 3, cc = u & 7, cs = cc ^ (row & 7);
      st[i] = *(const short8*)(Kb + (size_t)(kb + row) * DKH + cs * 8);
    }
    __syncthreads();
#pragma unroll
    for (int i = 0; i < 4; ++i) {
      int u = i * 256 + tid;
      *(short8*)((char*)Ks + u * 16) = st[i];
    }
    __syncthreads();
#pragma unroll
    for (int kt = 0; kt < 8; ++kt) {
      int rowL = kt * 16 + l15;
      int c0 = quad ^ (rowL & 7);
      int c1 = (quad + 4) ^ (rowL & 7);
      short8 kf0 = *(const short8*)((const char*)Ks + rowL * 128 + c0 * 16);
      short8 kf1 = *(const short8*)((const char*)Ks + rowL * 128 + c1 * 16);
      f32x4 s = {};
      s = __builtin_amdgcn_mfma_f32_16x16x32_bf16(qf0, kf0, s, 0, 0, 0);
      s = __builtin_amdgcn_mfma_f32_16x16x32_bf16(qf1, kf1, s, 0, 0, 0);
      int mk = mb[kb + rowL];
#pragma unroll
      for (int r = 0; r < 4; ++r) {
        float sv = mk ? -3e38f : s[r];
        float mn = fmaxf(m[r], sv);
        l[r] = l[r] * exp2f(m[r] - mn) + exp2f(sv - mn);
        m[r] = mn;
      }
    }
  }
  // combine (m,l) across the 16 lanes of each quad
#pragma unroll
  for (int j = 1; j < 16; j <<= 1) {
#pragma unroll
    for (int r = 0; r < 4; ++r) {
      float mo = __shfl_xor(m[r], j);
      float lo = __shfl_xor(l[r], j);
      float mn = fmaxf(m[r], mo);
      l[r] = l[r] * exp2f(m[r] - mn) + lo * exp2f(mo - mn);
      m[r] = mn;
    }
  }
  float invl[4];
#pragma unroll
  for (int r = 0; r < 4; ++r) invl[r] = 1.f / l[r];

  // ---- pass B: p = exp2(s-m)/l * bias; write p_attn; O += P@V ----
  f32x4 o[4] = {};
  u16* Pw = Ps[w];
  const size_t prow = ((size_t)bh * S_LEN + qw + quad * 4);

  for (int c = 0; c < 16; ++c) {
    const int kb = c * 128;
    short8 stk[4], stv[4];
#pragma unroll
    for (int i = 0; i < 4; ++i) {
      int u = i * 256 + tid;
      { int row = u >> 3, cc = u & 7, cs = cc ^ (row & 7);
        stk[i] = *(const short8*)(Kb + (size_t)(kb + row) * DKH + cs * 8); }
      { int row = u >> 4, cc = u & 15, cs = cc ^ (row & 7);
        stv[i] = *(const short8*)(Vb + (size_t)row * S_LEN + kb + cs * 8); }
    }
    __syncthreads();
#pragma unroll
    for (int i = 0; i < 4; ++i) {
      int u = i * 256 + tid;
      *(short8*)((char*)Ks + u * 16) = stk[i];
      *(short8*)((char*)Vs + u * 16) = stv[i];
    }
    __syncthreads();
#pragma unroll
    for (int kt = 0; kt < 8; ++kt) {
      int rowL = kt * 16 + l15;
      int c0 = quad ^ (rowL & 7);
      int c1 = (quad + 4) ^ (rowL & 7);
      short8 kf0 = *(const short8*)((const char*)Ks + rowL * 128 + c0 * 16);
      short8 kf1 = *(const short8*)((const char*)Ks + rowL * 128 + c1 * 16);
      f32x4 s = {};
      s = __builtin_amdgcn_mfma_f32_16x16x32_bf16(qf0, kf0, s, 0, 0, 0);
      s = __builtin_amdgcn_mfma_f32_16x16x32_bf16(qf1, kf1, s, 0, 0, 0);
      int mk = mb[kb + rowL];
      size_t pidx = prow * S_LEN + kb + rowL;
#pragma unroll
      for (int r = 0; r < 4; ++r) {
        float sv = mk ? -3e38f : s[r];
        float p = exp2f(sv - m[r]) * invl[r];
        float bz = __builtin_nontemporal_load(bias + pidx + (size_t)r * S_LEN);
        float pwv = p * bz;
        __builtin_nontemporal_store(pwv, pout + pidx + (size_t)r * S_LEN);
        Pw[(quad * 4 + r) * 136 + rowL] = f2bf(pwv);   // C/D -> LDS (A-layout source)
      }
    }
    // PV over this 128-key chunk (per-wave P buffer: no barrier needed)
#pragma unroll
    for (int ks = 0; ks < 4; ++ks) {
      short8 pf = *(const short8*)((const char*)Pw + l15 * 272 + ks * 64 + quad * 16);
#pragma unroll
      for (int nt = 0; nt < 4; ++nt) {
        int rowV = nt * 16 + l15;
        int cs = (ks * 4 + quad) ^ (rowV & 7);
        short8 vf = *(const short8*)((const char*)Vs + rowV * 256 + cs * 16);
        o[nt] = __builtin_amdgcn_mfma_f32_16x16x32_bf16(pf, vf, o[nt], 0, 0, 0);
      }
    }
  }

#pragma unroll
  for (int nt = 0; nt < 4; ++nt) {
#pragma unroll
    for (int r = 0; r < 4; ++r) {
      int qrow = qw + quad * 4 + r;
      Oout[(size_t)(b * S_LEN + qrow) * DMODEL + h * DKH + nt * 16 + l15] = f2bf(o[nt][r]);
    }
  }
}

// ---------------- host ----------------
extern "C" void kernel_launch(void* const* d_in, const int* in_sizes, int n_in,
                              void* d_out, int out_size, void* d_ws, size_t ws_size,
                              hipStream_t stream) {
  const float* q    = (const float*)d_in[0];
  const float* k    = (const float*)d_in[1];
  const float* v    = (const float*)d_in[2];
  const int*   mask = (const int*)d_in[3];
  const float* bias = (const float*)d_in[4];
  const float* Wq   = (const float*)d_in[5];
  const float* bq   = (const float*)d_in[6];
  const float* Wk   = (const float*)d_in[7];
  const float* bk   = (const float*)d_in[8];
  const float* Wv   = (const float*)d_in[9];
  const float* bv   = (const float*)d_in[10];
  const float* Wo   = (const float*)d_in[11];
  const float* bo   = (const float*)d_in[12];

  float* outf = (float*)d_out;
  float* pout = outf + (size_t)2 * S_LEN * DMODEL;   // p_attn region after out

  char* ws = (char*)d_ws;
  const size_t MB = 1u << 20;
  u16* qb  = (u16*)(ws + 0 * MB);
  u16* kbf = (u16*)(ws + 8 * MB);
  u16* vbf = (u16*)(ws + 16 * MB);
  u16* WqT = (u16*)(ws + 24 * MB);
  u16* WkT = (u16*)(ws + 26 * MB);
  u16* WvT = (u16*)(ws + 28 * MB);
  u16* WoT = (u16*)(ws + 30 * MB);
  u16* QhP = (u16*)(ws + 32 * MB);
  u16* KhP = (u16*)(ws + 40 * MB);
  u16* VTP = (u16*)(ws + 48 * MB);
  u16* ObP = (u16*)(ws + 56 * MB);

  const int n4 = (2 * S_LEN * DMODEL) / 4;  // 1048576
  cvt_bf16_kernel<<<4096, 256, 0, stream>>>(q, qb, n4);
  cvt_bf16_kernel<<<4096, 256, 0, stream>>>(k, kbf, n4);
  cvt_bf16_kernel<<<4096, 256, 0, stream>>>(v, vbf, n4);

  dim3 tg(32, 32), tb(32, 8);
  transpose_cvt_kernel<<<tg, tb, 0, stream>>>(Wq, WqT, QSCALE);
  transpose_cvt_kernel<<<tg, tb, 0, stream>>>(Wk, WkT, 1.f);
  transpose_cvt_kernel<<<tg, tb, 0, stream>>>(Wv, WvT, 1.f);
  transpose_cvt_kernel<<<tg, tb, 0, stream>>>(Wo, WoT, 1.f);

  GemmArgs3 pa;
  pa.g[0] = {qb,  WqT, bq, (void*)QhP, QSCALE, 0};
  pa.g[1] = {kbf, WkT, bk, (void*)KhP, 1.f,    0};
  pa.g[2] = {vbf, WvT, bv, (void*)VTP, 1.f,    1};
  gemm128_kernel<<<dim3(8, 32, 3), 256, 0, stream>>>(pa);

  attn_kernel<<<dim3(32, 32), 256, 0, stream>>>(QhP, KhP, VTP, mask, bias, pout, ObP);

  GemmArgs3 pb;
  pb.g[0] = {ObP, WoT, bo, (void*)outf, 1.f, 2};
  pb.g[1] = pb.g[0];
  pb.g[2] = pb.g[0];
  gemm128_kernel<<<dim3(8, 32, 1), 256, 0, stream>>>(pb);
}